// Round 2
// baseline (4514.699 us; speedup 1.0000x reference)
//
#include <hip/hip_runtime.h>
#include <math.h>

// Problem constants
constexpr int NNODE = 23;
constexpr int NB    = 512;
constexpr int NTX   = 28;   // encoder days
constexpr int NTY   = 7;    // decoder days
constexpr int DIN   = 128;
constexpr int DOUT  = 64;
constexpr int DH    = 128;
constexpr int MM    = NNODE * NB;        // 11776 sequences
constexpr int KX0   = DOUT + 1;          // 65 (layer0 input width)
constexpr int G4    = 4 * DH;            // 512 gate columns

// ---------------------------------------------------------------------------
// prep: build transposed concatenated weights W0cat[193][512], W1cat[256][512]
// and combined biases b0,b1 (bih+bhh).
// ---------------------------------------------------------------------------
__global__ void k_prep(const float* __restrict__ Wih0, const float* __restrict__ Whh0,
                       const float* __restrict__ bih0, const float* __restrict__ bhh0,
                       const float* __restrict__ Wih1, const float* __restrict__ Whh1,
                       const float* __restrict__ bih1, const float* __restrict__ bhh1,
                       float* __restrict__ W0c, float* __restrict__ W1c,
                       float* __restrict__ b0, float* __restrict__ b1)
{
    int idx = blockIdx.x * blockDim.x + threadIdx.x;
    const int S0 = (KX0 + DH) * G4;       // 193*512
    const int S1 = S0 + (DH + DH) * G4;   // + 256*512
    if (idx < S0) {
        int k = idx / G4, j = idx - k * G4;
        W0c[idx] = (k < KX0) ? Wih0[j * KX0 + k] : Whh0[j * DH + (k - KX0)];
    } else if (idx < S1) {
        int i2 = idx - S0;
        int k = i2 / G4, j = i2 - k * G4;
        W1c[i2] = (k < DH) ? Wih1[j * DH + k] : Whh1[j * DH + (k - DH)];
    } else if (idx < S1 + G4) {
        int j = idx - S1;
        b0[j] = bih0[j] + bhh0[j];
    } else if (idx < S1 + 2 * G4) {
        int j = idx - S1 - G4;
        b1[j] = bih1[j] + bhh1[j];
    }
}

// infdot[m] = sum_d x_infection[b][d][n] * fc_w[128+d],  m = n*NB + b
__global__ void k_infdot(const float* __restrict__ xinf, const float* __restrict__ fcw,
                         float* __restrict__ idot)
{
    int m = blockIdx.x * blockDim.x + threadIdx.x;
    if (m < MM) {
        int n = m / NB, b = m - n * NB;
        float s = 0.f;
        for (int d = 0; d < NTX; ++d)
            s += xinf[(b * NTX + d) * NNODE + n] * fcw[DH + d];
        idot[m] = s;
    }
}

// ---------------------------------------------------------------------------
// GCN: one block per (b,t). seq[t][m][0..63] = relu(DAD @ (x@Wg)) * scale[n],
// seq[t][m][64] = infection.  m = n*NB + b  (time-major for the LSTM scan).
// ---------------------------------------------------------------------------
__global__ __launch_bounds__(256)
void k_gcn(const float* __restrict__ x, const float* __restrict__ adjs,
           const float* __restrict__ xinf, const float* __restrict__ dayo,
           const float* __restrict__ v, const float* __restrict__ Wg,
           float* __restrict__ seq)
{
    int bt = blockIdx.x;              // b*NTX + t
    int b = bt / NTX, t = bt - b * NTX;
    __shared__ float sA[NNODE * NNODE];
    __shared__ float sdinv[NNODE];
    __shared__ float sscale[NNODE];
    __shared__ float sX[NNODE * DIN];
    __shared__ float sW[DIN * DOUT];
    __shared__ float sF[NNODE * DOUT];
    int tid = threadIdx.x;

    const float* adj0 = adjs + (size_t)bt * NNODE * NNODE;
    for (int i = tid; i < NNODE * NNODE; i += 256) {
        int n = i / NNODE, m2 = i - n * NNODE;
        sA[i] = adj0[i] + (n == m2 ? 1.f : 0.f);
    }
    const float* x0 = x + (size_t)bt * NNODE * DIN;
    for (int i = tid; i < NNODE * DIN; i += 256) sX[i] = x0[i];
    for (int i = tid; i < DIN * DOUT; i += 256) sW[i] = Wg[i];
    __syncthreads();

    if (tid < NNODE) {
        float s = 0.f;
        for (int m2 = 0; m2 < NNODE; ++m2) s += sA[tid * NNODE + m2];
        sdinv[tid] = rsqrtf(s);
        float vv = v[tid];
        sscale[tid] = __expf(vv * vv * dayo[b]);
    }
    __syncthreads();

    // feat = x @ Wg : [23][64]
    for (int i = tid; i < NNODE * DOUT; i += 256) {
        int n = i / DOUT, o = i - n * DOUT;
        float acc = 0.f;
        for (int k = 0; k < DIN; ++k) acc = fmaf(sX[n * DIN + k], sW[k * DOUT + o], acc);
        sF[i] = acc;
    }
    __syncthreads();

    // out = relu(dinv[n] * sum_m tA[n][m]*dinv[m]*feat[m][o]) * scale[n]
    for (int i = tid; i < NNODE * DOUT; i += 256) {
        int n = i / DOUT, o = i - n * DOUT;
        float acc = 0.f;
        for (int m2 = 0; m2 < NNODE; ++m2)
            acc = fmaf(sA[n * NNODE + m2] * sdinv[m2], sF[m2 * DOUT + o], acc);
        acc *= sdinv[n];
        acc = fmaxf(acc, 0.f) * sscale[n];
        seq[((size_t)t * MM + n * NB + b) * KX0 + o] = acc;
    }
    if (tid < NNODE) {
        seq[((size_t)t * MM + tid * NB + b) * KX0 + DOUT] = xinf[(size_t)bt * NNODE + tid];
    }
}

// x2[m][d] = mean over t of seq[t][m][d]
__global__ void k_mean(const float* __restrict__ seq, float* __restrict__ x2)
{
    int idx = blockIdx.x * blockDim.x + threadIdx.x;
    if (idx < MM * KX0) {
        float s = 0.f;
        for (int t = 0; t < NTX; ++t) s += seq[(size_t)t * MM * KX0 + idx];
        x2[idx] = s * (1.f / NTX);
    }
}

// ---------------------------------------------------------------------------
// Fused LSTM step: g = [xt | h] @ Wcat + bias ; gates ; in-place h,c update.
// Block = 32 rows x 512 gate cols, 256 threads; thread owns 4 rows x
// (4 hidden units x 4 gates) so gate fusion is thread-local.
// EPI: decoder layer-1 epilogue = fused FC + relu + transposed store to out.
// ---------------------------------------------------------------------------
template<int KX, bool EPI>
__global__ __launch_bounds__(256)
void k_lstm(const float* __restrict__ xt, const float* __restrict__ Wcat,
            const float* __restrict__ bias, float* __restrict__ h, float* __restrict__ c,
            const float* __restrict__ fcw, const float* __restrict__ idot,
            const float* __restrict__ fcbp, float* __restrict__ out, int tdec)
{
    constexpr int KTOT = KX + DH;
    __shared__ float sA[32 * KTOT];
    __shared__ float sWt[16 * G4];
    int tid = threadIdx.x;
    int tx = tid & 31, ty = tid >> 5;
    int row0 = blockIdx.x * 32;

    // A tile: [32][KTOT] = [xt | h]
    for (int i = tid; i < 32 * KTOT; i += 256) {
        int r = i / KTOT, k = i - r * KTOT;
        sA[i] = (k < KX) ? xt[(size_t)(row0 + r) * KX + k]
                         : h[(size_t)(row0 + r) * DH + (k - KX)];
    }

    float acc[4][16];
#pragma unroll
    for (int rr = 0; rr < 4; ++rr)
#pragma unroll
        for (int cc = 0; cc < 16; ++cc) acc[rr][cc] = 0.f;

    for (int k0 = 0; k0 < KTOT; k0 += 16) {
        const int ktile = (KTOT - k0 < 16) ? (KTOT - k0) : 16;
        __syncthreads();
        const float4* src = (const float4*)(Wcat + (size_t)k0 * G4);
        for (int i = tid; i < ktile * (G4 / 4); i += 256) ((float4*)sWt)[i] = src[i];
        __syncthreads();
        for (int kk = 0; kk < ktile; ++kk) {
            float a[4];
#pragma unroll
            for (int rr = 0; rr < 4; ++rr) a[rr] = sA[(ty + 8 * rr) * KTOT + k0 + kk];
            float4 w[4];
#pragma unroll
            for (int g = 0; g < 4; ++g) w[g] = *(const float4*)&sWt[kk * G4 + g * DH + tx * 4];
#pragma unroll
            for (int rr = 0; rr < 4; ++rr) {
#pragma unroll
                for (int g = 0; g < 4; ++g) {
                    acc[rr][g * 4 + 0] = fmaf(a[rr], w[g].x, acc[rr][g * 4 + 0]);
                    acc[rr][g * 4 + 1] = fmaf(a[rr], w[g].y, acc[rr][g * 4 + 1]);
                    acc[rr][g * 4 + 2] = fmaf(a[rr], w[g].z, acc[rr][g * 4 + 2]);
                    acc[rr][g * 4 + 3] = fmaf(a[rr], w[g].w, acc[rr][g * 4 + 3]);
                }
            }
        }
    }

    float fcp[4] = {0.f, 0.f, 0.f, 0.f};
#pragma unroll
    for (int rr = 0; rr < 4; ++rr) {
        int r = row0 + ty + 8 * rr;
        float4 c4 = *(const float4*)&c[(size_t)r * DH + tx * 4];
        float cold[4] = {c4.x, c4.y, c4.z, c4.w};
        float cn4[4], hn4[4];
#pragma unroll
        for (int jj = 0; jj < 4; ++jj) {
            int j = tx * 4 + jj;
            float gi = acc[rr][0 + jj]  + bias[j];
            float gf = acc[rr][4 + jj]  + bias[DH + j];
            float gG = acc[rr][8 + jj]  + bias[2 * DH + j];
            float go = acc[rr][12 + jj] + bias[3 * DH + j];
            float si = 1.f / (1.f + __expf(-gi));
            float sf = 1.f / (1.f + __expf(-gf));
            float so = 1.f / (1.f + __expf(-go));
            float cn = sf * cold[jj] + si * tanhf(gG);
            float hn = so * tanhf(cn);
            cn4[jj] = cn; hn4[jj] = hn;
            if (EPI) fcp[rr] += hn * fcw[j];
        }
        *(float4*)&c[(size_t)r * DH + tx * 4] = make_float4(cn4[0], cn4[1], cn4[2], cn4[3]);
        *(float4*)&h[(size_t)r * DH + tx * 4] = make_float4(hn4[0], hn4[1], hn4[2], hn4[3]);
    }

    if (EPI) {
        float fcb = fcbp[0];
#pragma unroll
        for (int rr = 0; rr < 4; ++rr) {
            float s = fcp[rr];
#pragma unroll
            for (int off = 16; off >= 1; off >>= 1) s += __shfl_xor(s, off, 64);
            if (tx == 0) {
                int r = row0 + ty + 8 * rr;
                int n = r / NB, b = r - n * NB;
                out[((size_t)b * NTY + tdec) * NNODE + n] = fmaxf(s + idot[r] + fcb, 0.f);
            }
        }
    }
}

// ---------------------------------------------------------------------------
extern "C" void kernel_launch(void* const* d_in, const int* in_sizes, int n_in,
                              void* d_out, int out_size, void* d_ws, size_t ws_size,
                              hipStream_t stream)
{
    const float* x    = (const float*)d_in[0];
    const float* adjs = (const float*)d_in[1];
    const float* xinf = (const float*)d_in[2];
    const float* dayo = (const float*)d_in[3];
    const float* v    = (const float*)d_in[4];
    const float* Wg   = (const float*)d_in[5];
    const float* Wih0 = (const float*)d_in[6];
    const float* Whh0 = (const float*)d_in[7];
    const float* bih0 = (const float*)d_in[8];
    const float* bhh0 = (const float*)d_in[9];
    const float* Wih1 = (const float*)d_in[10];
    const float* Whh1 = (const float*)d_in[11];
    const float* bih1 = (const float*)d_in[12];
    const float* bhh1 = (const float*)d_in[13];
    const float* fcw  = (const float*)d_in[14];
    const float* fcb  = (const float*)d_in[15];
    float* out = (float*)d_out;

    float* ws = (float*)d_ws;
    size_t o = 0;
    float* seq = ws + o; o += (size_t)NTX * MM * KX0;   // encoder lstm inputs, time-major
    float* x2  = ws + o; o += (size_t)MM * KX0;         // decoder input (mean over t)
    float* hc  = ws + o; o += (size_t)4 * MM * DH;      // h0,c0,h1,c1
    float* h0 = hc, *c0 = hc + (size_t)MM * DH;
    float* h1 = hc + (size_t)2 * MM * DH, *c1 = hc + (size_t)3 * MM * DH;
    float* W0c = ws + o; o += (size_t)(KX0 + DH) * G4;  // [193][512]
    float* W1c = ws + o; o += (size_t)(DH + DH) * G4;   // [256][512]
    float* b0  = ws + o; o += G4;
    float* b1  = ws + o; o += G4;
    float* idot = ws + o; o += MM;

    const int PREP_TOT = (KX0 + DH) * G4 + (DH + DH) * G4 + 2 * G4;
    k_prep<<<(PREP_TOT + 255) / 256, 256, 0, stream>>>(Wih0, Whh0, bih0, bhh0,
                                                       Wih1, Whh1, bih1, bhh1,
                                                       W0c, W1c, b0, b1);
    hipMemsetAsync(hc, 0, (size_t)4 * MM * DH * sizeof(float), stream);
    k_infdot<<<(MM + 255) / 256, 256, 0, stream>>>(xinf, fcw, idot);
    k_gcn<<<NB * NTX, 256, 0, stream>>>(x, adjs, xinf, dayo, v, Wg, seq);
    k_mean<<<(MM * KX0 + 255) / 256, 256, 0, stream>>>(seq, x2);

    // encoder: interleave layer0(t), layer1(t)
    for (int t = 0; t < NTX; ++t) {
        k_lstm<KX0, false><<<MM / 32, 256, 0, stream>>>(seq + (size_t)t * MM * KX0,
                                                        W0c, b0, h0, c0,
                                                        nullptr, nullptr, nullptr, nullptr, 0);
        k_lstm<DH, false><<<MM / 32, 256, 0, stream>>>(h0, W1c, b1, h1, c1,
                                                       nullptr, nullptr, nullptr, nullptr, 0);
    }
    // decoder: constant input x2; layer1 fuses FC+relu+transpose into d_out
    for (int t = 0; t < NTY; ++t) {
        k_lstm<KX0, false><<<MM / 32, 256, 0, stream>>>(x2, W0c, b0, h0, c0,
                                                        nullptr, nullptr, nullptr, nullptr, 0);
        k_lstm<DH, true><<<MM / 32, 256, 0, stream>>>(h0, W1c, b1, h1, c1,
                                                      fcw, idot, fcb, out, t);
    }
}

// Round 3
// 1560.852 us; speedup vs baseline: 2.8925x; 2.8925x over previous
//
#include <hip/hip_runtime.h>
#include <math.h>

typedef unsigned short u16;
typedef u16 u16x8 __attribute__((ext_vector_type(8)));
typedef __bf16 bf16x8 __attribute__((ext_vector_type(8)));
typedef float f32x4 __attribute__((ext_vector_type(4)));

constexpr int NNODE = 23;
constexpr int NB    = 512;
constexpr int NTX   = 28;
constexpr int NTY   = 7;
constexpr int DIN   = 128;
constexpr int DOUT  = 64;
constexpr int DH    = 128;
constexpr int MM    = NNODE * NB;   // 11776 = 256 * 46
constexpr int XW0   = 96;           // padded layer0 x-width (65 -> 96, 16B-aligned rows)
constexpr int K0    = XW0 + DH;     // 224 = 7 k-tiles
constexpr int K1    = DH + DH;      // 256 = 8 k-tiles
constexpr int G4    = 4 * DH;       // 512 gate cols

__device__ __forceinline__ u16 f2bf(float f) {
    unsigned x = __float_as_uint(f);
    return (u16)((x + 0x7fffu + ((x >> 16) & 1u)) >> 16);   // RNE
}
__device__ __forceinline__ float bf2f(u16 u) { return __uint_as_float(((unsigned)u) << 16); }
__device__ __forceinline__ float sigm(float x)  { return __fdividef(1.f, 1.f + __expf(-x)); }
__device__ __forceinline__ float tanh_f(float x){ return __fdividef(2.f, 1.f + __expf(-2.f * x)) - 1.f; }

// ---------------------------------------------------------------------------
// prep: Wt0[512][224] bf16 = [Wih0 | pad | Whh0], Wt1[512][256] bf16 = [Wih1 | Whh1]
// (input layout [4H][K] is already the MFMA-B-friendly transposed layout).
// b0,b1 f32 = bih + bhh.
// ---------------------------------------------------------------------------
__global__ void k_prep(const float* __restrict__ Wih0, const float* __restrict__ Whh0,
                       const float* __restrict__ bih0, const float* __restrict__ bhh0,
                       const float* __restrict__ Wih1, const float* __restrict__ Whh1,
                       const float* __restrict__ bih1, const float* __restrict__ bhh1,
                       u16* __restrict__ Wt0, u16* __restrict__ Wt1,
                       float* __restrict__ b0, float* __restrict__ b1)
{
    int idx = blockIdx.x * blockDim.x + threadIdx.x;
    const int S0 = G4 * K0, S1 = S0 + G4 * K1;
    if (idx < S0) {
        int c = idx / K0, k = idx - c * K0;
        float val = 0.f;
        if (k < DOUT + 1) val = Wih0[c * (DOUT + 1) + k];
        else if (k >= XW0) val = Whh0[c * DH + (k - XW0)];
        Wt0[idx] = f2bf(val);
    } else if (idx < S1) {
        int i2 = idx - S0;
        int c = i2 / K1, k = i2 - c * K1;
        float val = (k < DH) ? Wih1[c * DH + k] : Whh1[c * DH + (k - DH)];
        Wt1[i2] = f2bf(val);
    } else if (idx < S1 + G4) {
        int j = idx - S1; b0[j] = bih0[j] + bhh0[j];
    } else if (idx < S1 + 2 * G4) {
        int j = idx - S1 - G4; b1[j] = bih1[j] + bhh1[j];
    }
}

// infdot[m] = sum_d x_infection[b][d][n] * fc_w[128+d],  m = n*NB + b  (f32, exact)
__global__ void k_infdot(const float* __restrict__ xinf, const float* __restrict__ fcw,
                         float* __restrict__ idot)
{
    int m = blockIdx.x * blockDim.x + threadIdx.x;
    if (m < MM) {
        int n = m / NB, b = m - n * NB;
        float s = 0.f;
        for (int d = 0; d < NTX; ++d)
            s += xinf[(b * NTX + d) * NNODE + n] * fcw[DH + d];
        idot[m] = s;
    }
}

// ---------------------------------------------------------------------------
// GCN (f32 math, bf16 stores): seqb[t][m][0..63] = relu(DAD @ (x@Wg))*scale,
// [64] = infection, [65..95] = 0.   m = n*NB + b, row stride XW0=96.
// ---------------------------------------------------------------------------
__global__ __launch_bounds__(256)
void k_gcn(const float* __restrict__ x, const float* __restrict__ adjs,
           const float* __restrict__ xinf, const float* __restrict__ dayo,
           const float* __restrict__ v, const float* __restrict__ Wg,
           u16* __restrict__ seqb)
{
    int bt = blockIdx.x;              // b*NTX + t
    int b = bt / NTX, t = bt - b * NTX;
    __shared__ float sA[NNODE * NNODE];
    __shared__ float sdinv[NNODE];
    __shared__ float sscale[NNODE];
    __shared__ float sX[NNODE * DIN];
    __shared__ float sW[DIN * DOUT];
    __shared__ float sF[NNODE * DOUT];
    int tid = threadIdx.x;

    const float* adj0 = adjs + (size_t)bt * NNODE * NNODE;
    for (int i = tid; i < NNODE * NNODE; i += 256) {
        int n = i / NNODE, m2 = i - n * NNODE;
        sA[i] = adj0[i] + (n == m2 ? 1.f : 0.f);
    }
    const float* x0 = x + (size_t)bt * NNODE * DIN;
    for (int i = tid; i < NNODE * DIN; i += 256) sX[i] = x0[i];
    for (int i = tid; i < DIN * DOUT; i += 256) sW[i] = Wg[i];
    __syncthreads();

    if (tid < NNODE) {
        float s = 0.f;
        for (int m2 = 0; m2 < NNODE; ++m2) s += sA[tid * NNODE + m2];
        sdinv[tid] = rsqrtf(s);
        float vv = v[tid];
        sscale[tid] = __expf(vv * vv * dayo[b]);
    }
    __syncthreads();

    for (int i = tid; i < NNODE * DOUT; i += 256) {
        int n = i / DOUT, o = i - n * DOUT;
        float acc = 0.f;
        for (int k = 0; k < DIN; ++k) acc = fmaf(sX[n * DIN + k], sW[k * DOUT + o], acc);
        sF[i] = acc;
    }
    __syncthreads();

    for (int i = tid; i < NNODE * DOUT; i += 256) {
        int n = i / DOUT, o = i - n * DOUT;
        float acc = 0.f;
        for (int m2 = 0; m2 < NNODE; ++m2)
            acc = fmaf(sA[n * NNODE + m2] * sdinv[m2], sF[m2 * DOUT + o], acc);
        acc *= sdinv[n];
        acc = fmaxf(acc, 0.f) * sscale[n];
        seqb[((size_t)t * MM + n * NB + b) * XW0 + o] = f2bf(acc);
    }
    // zero pad cols 65..95
    for (int i = tid; i < NNODE * (XW0 - DOUT - 1); i += 256) {
        int n = i / (XW0 - DOUT - 1), o2 = DOUT + 1 + i - n * (XW0 - DOUT - 1);
        seqb[((size_t)t * MM + n * NB + b) * XW0 + o2] = 0;
    }
    if (tid < NNODE)
        seqb[((size_t)t * MM + tid * NB + b) * XW0 + DOUT] = f2bf(xinf[(size_t)bt * NNODE + tid]);
}

// x2b[m][d] = mean over t of seqb[t][m][d]  (f32 accumulate)
__global__ void k_mean(const u16* __restrict__ seqb, u16* __restrict__ x2b)
{
    int idx = blockIdx.x * blockDim.x + threadIdx.x;
    if (idx < MM * XW0) {
        float s = 0.f;
        for (int t = 0; t < NTX; ++t) s += bf2f(seqb[(size_t)t * MM * XW0 + idx]);
        x2b[idx] = f2bf(s * (1.f / NTX));
    }
}

// ---------------------------------------------------------------------------
// MFMA LSTM step. Block: 46 real rows (padded to 48) x 512 gate cols, 512 thr
// = 8 waves; wave w: 48 rows x c-tiles {w, 8+w, 16+w, 24+w} -> gate quadruple
// (i,f,g,o) for hidden unit j = 16*w + (lane&15) is thread-local.
// A = [xsrc(XW) | hrec(128)] staged bf16 in LDS (stride K+8: 2-way banks, free).
// B = Wt[c][k] read direct from global (L2-resident), 1-deep reg double-buffer.
// Epilogue: f32 bias + gates + in-place c(f32)/h(bf16) update.
// EPI: decoder L1 fused FC + relu + transposed store.
// ---------------------------------------------------------------------------
template<int XW, bool EPI>
__global__ __launch_bounds__(512)
void k_step(const u16* __restrict__ xsrc, const u16* __restrict__ Wt,
            const float* __restrict__ bias, u16* __restrict__ hrec,
            float* __restrict__ cst,
            const float* __restrict__ fcw, const float* __restrict__ idot,
            const float* __restrict__ fcbp, float* __restrict__ out, int tdec)
{
    constexpr int K   = XW + DH;
    constexpr int KT  = K / 32;
    constexpr int LDA = K + 8;
    constexpr int CH  = XW / 8 + DH / 8;   // ushort8 chunks per row
    __shared__ u16 sAm[48 * LDA];
    __shared__ float fcbuf[48];
    const int tid  = threadIdx.x;
    const int w    = tid >> 6, lane = tid & 63;
    const int row0 = blockIdx.x * 46;

    if (EPI && tid < 48) fcbuf[tid] = 0.f;

    // stage A tile: [48][K] = [x | h], rows 46..47 zero
    for (int i = tid; i < 48 * CH; i += 512) {
        int r = i / CH, ck = i - r * CH;
        u16x8 val;
        if (r < 46) {
            int gr = row0 + r;
            val = (ck < XW / 8)
                ? *(const u16x8*)(xsrc + (size_t)gr * XW + ck * 8)
                : *(const u16x8*)(hrec + (size_t)gr * DH + (ck - XW / 8) * 8);
        } else {
#pragma unroll
            for (int q = 0; q < 8; ++q) val[q] = 0;
        }
        *(u16x8*)(sAm + r * LDA + ck * 8) = val;
    }
    __syncthreads();

    const int lr = lane & 15, kg = lane >> 4;
    const u16* a0 = sAm + (size_t)lr * LDA + kg * 8;
    const u16* wb0 = Wt + (size_t)(0 * DH + 16 * w + lr) * K + kg * 8;
    const u16* wb1 = Wt + (size_t)(1 * DH + 16 * w + lr) * K + kg * 8;
    const u16* wb2 = Wt + (size_t)(2 * DH + 16 * w + lr) * K + kg * 8;
    const u16* wb3 = Wt + (size_t)(3 * DH + 16 * w + lr) * K + kg * 8;

    f32x4 acc[3][4];
#pragma unroll
    for (int m = 0; m < 3; ++m)
#pragma unroll
        for (int g = 0; g < 4; ++g)
#pragma unroll
            for (int q = 0; q < 4; ++q) acc[m][g][q] = 0.f;

    bf16x8 Ac[3], An[3], Bc[4], Bn[4];
#pragma unroll
    for (int m = 0; m < 3; ++m) Ac[m] = *(const bf16x8*)(a0 + m * 16 * LDA);
    Bc[0] = *(const bf16x8*)wb0; Bc[1] = *(const bf16x8*)wb1;
    Bc[2] = *(const bf16x8*)wb2; Bc[3] = *(const bf16x8*)wb3;

#pragma unroll
    for (int kt = 0; kt < KT; ++kt) {
        if (kt + 1 < KT) {
#pragma unroll
            for (int m = 0; m < 3; ++m)
                An[m] = *(const bf16x8*)(a0 + m * 16 * LDA + (kt + 1) * 32);
            Bn[0] = *(const bf16x8*)(wb0 + (kt + 1) * 32);
            Bn[1] = *(const bf16x8*)(wb1 + (kt + 1) * 32);
            Bn[2] = *(const bf16x8*)(wb2 + (kt + 1) * 32);
            Bn[3] = *(const bf16x8*)(wb3 + (kt + 1) * 32);
        }
#pragma unroll
        for (int m = 0; m < 3; ++m)
#pragma unroll
            for (int g = 0; g < 4; ++g)
                acc[m][g] = __builtin_amdgcn_mfma_f32_16x16x32_bf16(Ac[m], Bc[g], acc[m][g], 0, 0, 0);
        if (kt + 1 < KT) {
#pragma unroll
            for (int m = 0; m < 3; ++m) Ac[m] = An[m];
#pragma unroll
            for (int g = 0; g < 4; ++g) Bc[g] = Bn[g];
        }
    }

    const int jj = 16 * w + lr;                       // hidden unit
    const float bi = bias[jj], bff = bias[DH + jj];
    const float bg = bias[2 * DH + jj], bo = bias[3 * DH + jj];
    const float fw = EPI ? fcw[jj] : 0.f;

#pragma unroll
    for (int m = 0; m < 3; ++m) {
#pragma unroll
        for (int q = 0; q < 4; ++q) {
            int r  = m * 16 + kg * 4 + q;              // 0..47
            int gr = row0 + r;
            bool valid = (r < 46);
            float cold = valid ? cst[(size_t)gr * DH + jj] : 0.f;
            float gi = acc[m][0][q] + bi;
            float gf = acc[m][1][q] + bff;
            float gg = acc[m][2][q] + bg;
            float go = acc[m][3][q] + bo;
            float cn = sigm(gf) * cold + sigm(gi) * tanh_f(gg);
            float hn = sigm(go) * tanh_f(cn);
            if (valid) {
                cst[(size_t)gr * DH + jj]  = cn;
                hrec[(size_t)gr * DH + jj] = f2bf(hn);
            }
            if (EPI) {
                float p = hn * fw;
                p += __shfl_xor(p, 1, 64);
                p += __shfl_xor(p, 2, 64);
                p += __shfl_xor(p, 4, 64);
                p += __shfl_xor(p, 8, 64);
                if (lr == 0 && valid) atomicAdd(&fcbuf[r], p);
            }
        }
    }

    if (EPI) {
        __syncthreads();
        if (tid < 46) {
            int gr = row0 + tid;
            int n = gr >> 9, b = gr & (NB - 1);
            out[((size_t)b * NTY + tdec) * NNODE + n] =
                fmaxf(fcbuf[tid] + idot[gr] + fcbp[0], 0.f);
        }
    }
}

// ---------------------------------------------------------------------------
extern "C" void kernel_launch(void* const* d_in, const int* in_sizes, int n_in,
                              void* d_out, int out_size, void* d_ws, size_t ws_size,
                              hipStream_t stream)
{
    const float* x    = (const float*)d_in[0];
    const float* adjs = (const float*)d_in[1];
    const float* xinf = (const float*)d_in[2];
    const float* dayo = (const float*)d_in[3];
    const float* v    = (const float*)d_in[4];
    const float* Wg   = (const float*)d_in[5];
    const float* Wih0 = (const float*)d_in[6];
    const float* Whh0 = (const float*)d_in[7];
    const float* bih0 = (const float*)d_in[8];
    const float* bhh0 = (const float*)d_in[9];
    const float* Wih1 = (const float*)d_in[10];
    const float* Whh1 = (const float*)d_in[11];
    const float* bih1 = (const float*)d_in[12];
    const float* bhh1 = (const float*)d_in[13];
    const float* fcw  = (const float*)d_in[14];
    const float* fcb  = (const float*)d_in[15];
    float* out = (float*)d_out;

    char* p = (char*)d_ws;
    auto alloc = [&](size_t bytes) { void* r = p; p += (bytes + 255) & ~(size_t)255; return r; };
    u16*   seqb = (u16*)alloc((size_t)NTX * MM * XW0 * 2);
    u16*   x2b  = (u16*)alloc((size_t)MM * XW0 * 2);
    char*  state = p;
    u16*   hb0  = (u16*)alloc((size_t)MM * DH * 2);
    u16*   hb1  = (u16*)alloc((size_t)MM * DH * 2);
    float* c0   = (float*)alloc((size_t)MM * DH * 4);
    float* c1   = (float*)alloc((size_t)MM * DH * 4);
    size_t state_bytes = (size_t)(p - state);
    u16*   Wt0  = (u16*)alloc((size_t)G4 * K0 * 2);
    u16*   Wt1  = (u16*)alloc((size_t)G4 * K1 * 2);
    float* b0   = (float*)alloc(G4 * 4);
    float* b1   = (float*)alloc(G4 * 4);
    float* idot = (float*)alloc(MM * 4);

    const int PREP_TOT = G4 * K0 + G4 * K1 + 2 * G4;
    k_prep<<<(PREP_TOT + 255) / 256, 256, 0, stream>>>(Wih0, Whh0, bih0, bhh0,
                                                       Wih1, Whh1, bih1, bhh1,
                                                       Wt0, Wt1, b0, b1);
    hipMemsetAsync(state, 0, state_bytes, stream);
    k_infdot<<<(MM + 255) / 256, 256, 0, stream>>>(xinf, fcw, idot);
    k_gcn<<<NB * NTX, 256, 0, stream>>>(x, adjs, xinf, dayo, v, Wg, seqb);
    k_mean<<<(MM * XW0 + 255) / 256, 256, 0, stream>>>(seqb, x2b);

    // encoder
    for (int t = 0; t < NTX; ++t) {
        k_step<XW0, false><<<MM / 46, 512, 0, stream>>>(seqb + (size_t)t * MM * XW0,
                                                        Wt0, b0, hb0, c0,
                                                        nullptr, nullptr, nullptr, nullptr, 0);
        k_step<DH, false><<<MM / 46, 512, 0, stream>>>(hb0, Wt1, b1, hb1, c1,
                                                       nullptr, nullptr, nullptr, nullptr, 0);
    }
    // decoder
    for (int t = 0; t < NTY; ++t) {
        k_step<XW0, false><<<MM / 46, 512, 0, stream>>>(x2b, Wt0, b0, hb0, c0,
                                                        nullptr, nullptr, nullptr, nullptr, 0);
        k_step<DH, true><<<MM / 46, 512, 0, stream>>>(hb0, Wt1, b1, hb1, c1,
                                                      fcw, idot, fcb, out, t);
    }
}

// Round 5
// 1069.605 us; speedup vs baseline: 4.2209x; 1.4593x over previous
//
#include <hip/hip_runtime.h>
#include <math.h>

typedef unsigned short u16;
typedef u16 u16x8 __attribute__((ext_vector_type(8)));
typedef u16 u16x4 __attribute__((ext_vector_type(4)));
typedef __bf16 bf16x8 __attribute__((ext_vector_type(8)));
typedef float f32x4 __attribute__((ext_vector_type(4)));

constexpr int NNODE = 23;
constexpr int NB    = 512;
constexpr int NTX   = 28;
constexpr int NTY   = 7;
constexpr int DIN   = 128;
constexpr int DOUT  = 64;
constexpr int DH    = 128;
constexpr int MM    = NNODE * NB;   // 11776 = 256 * 46
constexpr int XW0   = 96;           // padded layer0 x-width
constexpr int K0    = XW0 + DH;     // 224 = 7 k-tiles
constexpr int K1    = DH + DH;      // 256 = 8 k-tiles
constexpr int G4    = 4 * DH;       // 512 gate cols
constexpr int ROWS  = 46;
constexpr int RPAD  = 48;
constexpr int LDX   = XW0 + 8;      // 104 (16B-aligned rows, rotating banks)
constexpr int LDH   = DH + 8;       // 136

__device__ __forceinline__ u16 f2bf(float f) {
    unsigned x = __float_as_uint(f);
    return (u16)((x + 0x7fffu + ((x >> 16) & 1u)) >> 16);   // RNE
}
__device__ __forceinline__ float bf2f(u16 u) { return __uint_as_float(((unsigned)u) << 16); }
__device__ __forceinline__ float sigm(float x)  { return __fdividef(1.f, 1.f + __expf(-x)); }
__device__ __forceinline__ float tanh_f(float x){ return __fdividef(2.f, 1.f + __expf(-2.f * x)) - 1.f; }

// ---------------------------------------------------------------------------
// prep: Wt0[512][224] bf16 = [Wih0 | pad | Whh0], Wt1[512][256] bf16,
// b0,b1 f32 = bih+bhh, Wgt[64][128] bf16 = Wg^T (MFMA-B layout for GCN feat).
// ---------------------------------------------------------------------------
__global__ void k_prep(const float* __restrict__ Wih0, const float* __restrict__ Whh0,
                       const float* __restrict__ bih0, const float* __restrict__ bhh0,
                       const float* __restrict__ Wih1, const float* __restrict__ Whh1,
                       const float* __restrict__ bih1, const float* __restrict__ bhh1,
                       const float* __restrict__ Wg,
                       u16* __restrict__ Wt0, u16* __restrict__ Wt1,
                       float* __restrict__ b0, float* __restrict__ b1,
                       u16* __restrict__ Wgt)
{
    int idx = blockIdx.x * blockDim.x + threadIdx.x;
    const int S0 = G4 * K0, S1 = S0 + G4 * K1;
    const int S2 = S1 + 2 * G4;
    if (idx < S0) {
        int c = idx / K0, k = idx - c * K0;
        float val = 0.f;
        if (k < DOUT + 1) val = Wih0[c * (DOUT + 1) + k];
        else if (k >= XW0) val = Whh0[c * DH + (k - XW0)];
        Wt0[idx] = f2bf(val);
    } else if (idx < S1) {
        int i2 = idx - S0;
        int c = i2 / K1, k = i2 - c * K1;
        float val = (k < DH) ? Wih1[c * DH + k] : Whh1[c * DH + (k - DH)];
        Wt1[i2] = f2bf(val);
    } else if (idx < S1 + G4) {
        int j = idx - S1; b0[j] = bih0[j] + bhh0[j];
    } else if (idx < S2) {
        int j = idx - S1 - G4; b1[j] = bih1[j] + bhh1[j];
    } else if (idx < S2 + DOUT * DIN) {
        int i2 = idx - S2;
        int o = i2 / DIN, k = i2 - o * DIN;
        Wgt[i2] = f2bf(Wg[k * DOUT + o]);
    }
}

// infdot[m] = sum_d x_infection[b][d][n] * fc_w[128+d],  m = n*NB + b
__global__ void k_infdot(const float* __restrict__ xinf, const float* __restrict__ fcw,
                         float* __restrict__ idot)
{
    int m = blockIdx.x * blockDim.x + threadIdx.x;
    if (m < MM) {
        int n = m / NB, b = m - n * NB;
        float s = 0.f;
        for (int d = 0; d < NTX; ++d)
            s += xinf[(b * NTX + d) * NNODE + n] * fcw[DH + d];
        idot[m] = s;
    }
}

// ---------------------------------------------------------------------------
// GCN: one block per (b,t), 4 waves. feat = x@Wg via MFMA (bf16 in, f32 acc);
// DAD + relu + scale in f32. seqb rows stride XW0=96, m = n*NB + b.
// ---------------------------------------------------------------------------
__global__ __launch_bounds__(256)
void k_gcn(const float* __restrict__ x, const float* __restrict__ adjs,
           const float* __restrict__ xinf, const float* __restrict__ dayo,
           const float* __restrict__ v, const u16* __restrict__ Wgt,
           u16* __restrict__ seqb)
{
    int bt = blockIdx.x;              // b*NTX + t
    int b = bt / NTX, t = bt - b * NTX;
    __shared__ __align__(16) u16 sXb[32 * LDH];      // x bf16, rows 23..31 zero
    __shared__ float sA[NNODE * NNODE];
    __shared__ float sdinv[NNODE];
    __shared__ float sscale[NNODE];
    __shared__ float sF[NNODE * 68];                 // feat f32, LDF=68
    int tid = threadIdx.x;
    const int w = tid >> 6, lane = tid & 63, lr = lane & 15, kg = lane >> 4;

    // stage x -> bf16 LDS (float4 coalesced)
    const float* x0 = x + (size_t)bt * NNODE * DIN;
    for (int i = tid; i < 32 * 32; i += 256) {
        int r = i >> 5, c4 = i & 31;
        u16x4 pk;
        if (r < NNODE) {
            float4 val = ((const float4*)x0)[r * 32 + c4];
            pk[0] = f2bf(val.x); pk[1] = f2bf(val.y); pk[2] = f2bf(val.z); pk[3] = f2bf(val.w);
        } else { pk[0] = pk[1] = pk[2] = pk[3] = 0; }
        *(u16x4*)(sXb + r * LDH + c4 * 4) = pk;
    }
    const float* adj0 = adjs + (size_t)bt * NNODE * NNODE;
    for (int i = tid; i < NNODE * NNODE; i += 256) {
        int n = i / NNODE, m2 = i - n * NNODE;
        sA[i] = adj0[i] + (n == m2 ? 1.f : 0.f);
    }
    __syncthreads();

    if (tid < NNODE) {
        float s = 0.f;
        for (int m2 = 0; m2 < NNODE; ++m2) s += sA[tid * NNODE + m2];
        sdinv[tid] = rsqrtf(s);
        float vv = v[tid];
        sscale[tid] = __expf(vv * vv * dayo[b]);
    }

    // feat via MFMA: wave w -> cols 16w..16w+15, two 16-row tiles
    {
        const u16* a0 = sXb + lr * LDH + kg * 8;
        const u16* wb = Wgt + (size_t)(16 * w + lr) * DIN + kg * 8;
        f32x4 acc[2];
#pragma unroll
        for (int m = 0; m < 2; ++m)
#pragma unroll
            for (int q = 0; q < 4; ++q) acc[m][q] = 0.f;
#pragma unroll
        for (int kt = 0; kt < 4; ++kt) {
            bf16x8 Bv  = *(const bf16x8*)(wb + kt * 32);
            bf16x8 A0v = *(const bf16x8*)(a0 + kt * 32);
            bf16x8 A1v = *(const bf16x8*)(a0 + 16 * LDH + kt * 32);
            acc[0] = __builtin_amdgcn_mfma_f32_16x16x32_bf16(A0v, Bv, acc[0], 0, 0, 0);
            acc[1] = __builtin_amdgcn_mfma_f32_16x16x32_bf16(A1v, Bv, acc[1], 0, 0, 0);
        }
#pragma unroll
        for (int m = 0; m < 2; ++m)
#pragma unroll
            for (int q = 0; q < 4; ++q) {
                int r = m * 16 + kg * 4 + q;
                if (r < NNODE) sF[r * 68 + 16 * w + lr] = acc[m][q];
            }
    }
    __syncthreads();

    // DAD + relu + scale (f32)
    for (int i = tid; i < NNODE * DOUT; i += 256) {
        int n = i / DOUT, o = i - n * DOUT;
        float acc = 0.f;
        for (int m2 = 0; m2 < NNODE; ++m2)
            acc = fmaf(sA[n * NNODE + m2] * sdinv[m2], sF[m2 * 68 + o], acc);
        acc *= sdinv[n];
        acc = fmaxf(acc, 0.f) * sscale[n];
        seqb[((size_t)t * MM + n * NB + b) * XW0 + o] = f2bf(acc);
    }
    for (int i = tid; i < NNODE * (XW0 - DOUT - 1); i += 256) {
        int n = i / (XW0 - DOUT - 1), o2 = DOUT + 1 + i - n * (XW0 - DOUT - 1);
        seqb[((size_t)t * MM + n * NB + b) * XW0 + o2] = 0;
    }
    if (tid < NNODE)
        seqb[((size_t)t * MM + tid * NB + b) * XW0 + DOUT] = f2bf(xinf[(size_t)bt * NNODE + tid]);
}

// ---------------------------------------------------------------------------
// GEMM helper: 48x512 gate pre-activations, A split across two LDS tiles at
// k-tile SPLIT. Per-wave: 3 m-tiles x 4 gate-tiles, 1-deep A/B prefetch.
// ---------------------------------------------------------------------------
template<int KT, int SPLIT, int LD0, int LD1>
__device__ __forceinline__ void gemm_ab(const u16* A0, const u16* A1,
    const u16* g0, const u16* g1, const u16* g2, const u16* g3,
    f32x4 (&acc)[3][4])
{
#pragma unroll
    for (int m = 0; m < 3; ++m)
#pragma unroll
        for (int g = 0; g < 4; ++g)
#pragma unroll
            for (int q = 0; q < 4; ++q) acc[m][g][q] = 0.f;

    bf16x8 Ac[3], An[3], Bc[4], Bn[4];
#pragma unroll
    for (int m = 0; m < 3; ++m) Ac[m] = *(const bf16x8*)(A0 + m * 16 * LD0);
    Bc[0] = *(const bf16x8*)g0; Bc[1] = *(const bf16x8*)g1;
    Bc[2] = *(const bf16x8*)g2; Bc[3] = *(const bf16x8*)g3;

#pragma unroll
    for (int kt = 0; kt < KT; ++kt) {
        if (kt + 1 < KT) {
            const int kn = kt + 1;
#pragma unroll
            for (int m = 0; m < 3; ++m)
                An[m] = *(const bf16x8*)((kn < SPLIT)
                        ? (A0 + m * 16 * LD0 + kn * 32)
                        : (A1 + m * 16 * LD1 + (kn - SPLIT) * 32));
            Bn[0] = *(const bf16x8*)(g0 + kn * 32); Bn[1] = *(const bf16x8*)(g1 + kn * 32);
            Bn[2] = *(const bf16x8*)(g2 + kn * 32); Bn[3] = *(const bf16x8*)(g3 + kn * 32);
        }
#pragma unroll
        for (int m = 0; m < 3; ++m)
#pragma unroll
            for (int g = 0; g < 4; ++g)
                acc[m][g] = __builtin_amdgcn_mfma_f32_16x16x32_bf16(Ac[m], Bc[g], acc[m][g], 0, 0, 0);
        if (kt + 1 < KT) {
#pragma unroll
            for (int m = 0; m < 3; ++m) Ac[m] = An[m];
#pragma unroll
            for (int g = 0; g < 4; ++g) Bc[g] = Bn[g];
        }
    }
}

__device__ __forceinline__ void epi_plain(const f32x4 (&acc)[3][4], float* cr,
    u16* sHd, float bi, float bf_, float bg, float bo, int kg, int jj)
{
#pragma unroll
    for (int m = 0; m < 3; ++m)
#pragma unroll
        for (int q = 0; q < 4; ++q) {
            int r = m * 16 + kg * 4 + q;
            float gi = acc[m][0][q] + bi, gf = acc[m][1][q] + bf_;
            float gg = acc[m][2][q] + bg, go = acc[m][3][q] + bo;
            float cn = sigm(gf) * cr[m * 4 + q] + sigm(gi) * tanh_f(gg);
            float hn = sigm(go) * tanh_f(cn);
            cr[m * 4 + q] = cn;
            if (r < ROWS) sHd[r * LDH + jj] = f2bf(hn);
        }
}

// ---------------------------------------------------------------------------
// Persistent LSTM scan: 256 blocks x 46 rows x 512 threads (8 waves).
// Whole 28-enc + 7-dec scan in one launch; h0/h1 in LDS, c0/c1 in registers;
// decoder mean accumulated in registers during encoder staging.
// Weights stream from L2 (each block reads full Wt once/step, no duplication).
// ---------------------------------------------------------------------------
__global__ __launch_bounds__(512, 2)
void k_scan(const u16* __restrict__ seqb,
            const u16* __restrict__ Wt0, const u16* __restrict__ Wt1,
            const float* __restrict__ b0, const float* __restrict__ b1,
            const float* __restrict__ fcw, const float* __restrict__ idot,
            const float* __restrict__ fcbp, float* __restrict__ out)
{
    __shared__ __align__(16) u16 sX [RPAD * LDX];
    __shared__ __align__(16) u16 sH0[RPAD * LDH];
    __shared__ __align__(16) u16 sH1[RPAD * LDH];
    __shared__ float fcbuf[RPAD];
    const int tid = threadIdx.x, w = tid >> 6, lane = tid & 63;
    const int lr = lane & 15, kg = lane >> 4;
    const int row0 = blockIdx.x * ROWS;
    const int jj = 16 * w + lr;

    // zero h state (pad rows stay zero forever; epilogues write only r<46)
    {
        u16x8 z;
#pragma unroll
        for (int q = 0; q < 8; ++q) z[q] = 0;
        for (int i = tid; i < RPAD * (LDH / 8); i += 512) {
            *(u16x8*)(sH0 + i * 8) = z;
            *(u16x8*)(sH1 + i * 8) = z;
        }
    }

    const float bi0 = b0[jj], bf0 = b0[DH + jj], bg0 = b0[2 * DH + jj], bo0 = b0[3 * DH + jj];
    const float bi1 = b1[jj], bf1 = b1[DH + jj], bg1 = b1[2 * DH + jj], bo1 = b1[3 * DH + jj];
    const float fw  = fcw[jj];
    const float fcb = fcbp[0];
    const float idv = (tid < ROWS) ? idot[row0 + tid] : 0.f;

    const u16* aX  = sX  + lr * LDX + kg * 8;
    const u16* aH0 = sH0 + lr * LDH + kg * 8;
    const u16* aH1 = sH1 + lr * LDH + kg * 8;
    const u16* w00 = Wt0 + (size_t)(0 * DH + jj) * K0 + kg * 8;
    const u16* w01 = Wt0 + (size_t)(1 * DH + jj) * K0 + kg * 8;
    const u16* w02 = Wt0 + (size_t)(2 * DH + jj) * K0 + kg * 8;
    const u16* w03 = Wt0 + (size_t)(3 * DH + jj) * K0 + kg * 8;
    const u16* w10 = Wt1 + (size_t)(0 * DH + jj) * K1 + kg * 8;
    const u16* w11 = Wt1 + (size_t)(1 * DH + jj) * K1 + kg * 8;
    const u16* w12 = Wt1 + (size_t)(2 * DH + jj) * K1 + kg * 8;
    const u16* w13 = Wt1 + (size_t)(3 * DH + jj) * K1 + kg * 8;

    float c0r[12], c1r[12];
#pragma unroll
    for (int i = 0; i < 12; ++i) { c0r[i] = 0.f; c1r[i] = 0.f; }
    float xs[16];
#pragma unroll
    for (int i = 0; i < 16; ++i) xs[i] = 0.f;

    f32x4 acc[3][4];

    // ---------------- encoder ----------------
    for (int t = 0; t < NTX; ++t) {
        // stage x tile (48 x 96 bf16) + accumulate decoder mean
#pragma unroll
        for (int ii = 0; ii < 2; ++ii) {
            int i = tid + ii * 512;
            if (i < 576) {
                int r = i / 12, ck = i - r * 12;
                u16x8 val;
                if (r < ROWS) val = *(const u16x8*)(seqb + (size_t)t * MM * XW0 +
                                                   (size_t)(row0 + r) * XW0 + ck * 8);
                else {
#pragma unroll
                    for (int q = 0; q < 8; ++q) val[q] = 0;
                }
                *(u16x8*)(sX + r * LDX + ck * 8) = val;
#pragma unroll
                for (int q = 0; q < 8; ++q) xs[ii * 8 + q] += bf2f(val[q]);
            }
        }
        __syncthreads();
        gemm_ab<7, 3, LDX, LDH>(aX, aH0, w00, w01, w02, w03, acc);
        __syncthreads();
        epi_plain(acc, c0r, sH0, bi0, bf0, bg0, bo0, kg, jj);
        __syncthreads();
        gemm_ab<8, 4, LDH, LDH>(aH0, aH1, w10, w11, w12, w13, acc);
        __syncthreads();
        epi_plain(acc, c1r, sH1, bi1, bf1, bg1, bo1, kg, jj);
        __syncthreads();
    }

    // ---------------- decoder: constant input = mean over encoder days ----
#pragma unroll
    for (int ii = 0; ii < 2; ++ii) {
        int i = tid + ii * 512;
        if (i < 576) {
            int r = i / 12, ck = i - r * 12;
            u16x8 mv;
#pragma unroll
            for (int q = 0; q < 8; ++q) mv[q] = f2bf(xs[ii * 8 + q] * (1.f / NTX));
            *(u16x8*)(sX + r * LDX + ck * 8) = mv;
        }
    }
    __syncthreads();

    for (int t = 0; t < NTY; ++t) {
        if (tid < RPAD) fcbuf[tid] = 0.f;
        gemm_ab<7, 3, LDX, LDH>(aX, aH0, w00, w01, w02, w03, acc);
        __syncthreads();   // gemm reads done + fcbuf zero visible
        epi_plain(acc, c0r, sH0, bi0, bf0, bg0, bo0, kg, jj);
        __syncthreads();
        gemm_ab<8, 4, LDH, LDH>(aH0, aH1, w10, w11, w12, w13, acc);
        __syncthreads();   // L1 gemm reads of sH1 done
        // L1 epilogue + fused FC
#pragma unroll
        for (int m = 0; m < 3; ++m)
#pragma unroll
            for (int q = 0; q < 4; ++q) {
                int r = m * 16 + kg * 4 + q;
                float gi = acc[m][0][q] + bi1, gf = acc[m][1][q] + bf1;
                float gg = acc[m][2][q] + bg1, go = acc[m][3][q] + bo1;
                float cn = sigm(gf) * c1r[m * 4 + q] + sigm(gi) * tanh_f(gg);
                float hn = sigm(go) * tanh_f(cn);
                c1r[m * 4 + q] = cn;
                if (r < ROWS) sH1[r * LDH + jj] = f2bf(hn);
                float p = hn * fw;
                p += __shfl_xor(p, 1, 64);
                p += __shfl_xor(p, 2, 64);
                p += __shfl_xor(p, 4, 64);
                p += __shfl_xor(p, 8, 64);
                if (lr == 0 && r < ROWS) atomicAdd(&fcbuf[r], p);
            }
        __syncthreads();   // atomics done
        if (tid < ROWS) {
            int gr = row0 + tid;
            int n = gr >> 9, bb = gr & (NB - 1);
            out[((size_t)bb * NTY + t) * NNODE + n] = fmaxf(fcbuf[tid] + idv + fcb, 0.f);
        }
        __syncthreads();
    }
}

// ---------------------------------------------------------------------------
extern "C" void kernel_launch(void* const* d_in, const int* in_sizes, int n_in,
                              void* d_out, int out_size, void* d_ws, size_t ws_size,
                              hipStream_t stream)
{
    const float* x    = (const float*)d_in[0];
    const float* adjs = (const float*)d_in[1];
    const float* xinf = (const float*)d_in[2];
    const float* dayo = (const float*)d_in[3];
    const float* v    = (const float*)d_in[4];
    const float* Wg   = (const float*)d_in[5];
    const float* Wih0 = (const float*)d_in[6];
    const float* Whh0 = (const float*)d_in[7];
    const float* bih0 = (const float*)d_in[8];
    const float* bhh0 = (const float*)d_in[9];
    const float* Wih1 = (const float*)d_in[10];
    const float* Whh1 = (const float*)d_in[11];
    const float* bih1 = (const float*)d_in[12];
    const float* bhh1 = (const float*)d_in[13];
    const float* fcw  = (const float*)d_in[14];
    const float* fcb  = (const float*)d_in[15];
    float* out = (float*)d_out;

    char* p = (char*)d_ws;
    auto alloc = [&](size_t bytes) { void* r = p; p += (bytes + 255) & ~(size_t)255; return r; };
    u16*   seqb = (u16*)alloc((size_t)NTX * MM * XW0 * 2);
    u16*   Wt0  = (u16*)alloc((size_t)G4 * K0 * 2);
    u16*   Wt1  = (u16*)alloc((size_t)G4 * K1 * 2);
    u16*   Wgt  = (u16*)alloc((size_t)DOUT * DIN * 2);
    float* b0   = (float*)alloc(G4 * 4);
    float* b1   = (float*)alloc(G4 * 4);
    float* idot = (float*)alloc(MM * 4);

    const int PREP_TOT = G4 * K0 + G4 * K1 + 2 * G4 + DOUT * DIN;
    k_prep<<<(PREP_TOT + 255) / 256, 256, 0, stream>>>(Wih0, Whh0, bih0, bhh0,
                                                       Wih1, Whh1, bih1, bhh1, Wg,
                                                       Wt0, Wt1, b0, b1, Wgt);
    k_infdot<<<(MM + 255) / 256, 256, 0, stream>>>(xinf, fcw, idot);
    k_gcn<<<NB * NTX, 256, 0, stream>>>(x, adjs, xinf, dayo, v, Wgt, seqb);
    k_scan<<<MM / ROWS, 512, 0, stream>>>(seqb, Wt0, Wt1, b0, b1, fcw, idot, fcb, out);
}

// Round 6
// 1049.371 us; speedup vs baseline: 4.3023x; 1.0193x over previous
//
#include <hip/hip_runtime.h>
#include <math.h>

typedef unsigned short u16;
typedef u16 u16x8 __attribute__((ext_vector_type(8)));
typedef u16 u16x4 __attribute__((ext_vector_type(4)));
typedef __bf16 bf16x8 __attribute__((ext_vector_type(8)));
typedef float f32x4 __attribute__((ext_vector_type(4)));

constexpr int NNODE = 23;
constexpr int NB    = 512;
constexpr int NTX   = 28;
constexpr int NTY   = 7;
constexpr int DIN   = 128;
constexpr int DOUT  = 64;
constexpr int DH    = 128;
constexpr int MM    = NNODE * NB;   // 11776 = 256 * 46
constexpr int XW0   = 96;           // padded layer0 x-width
constexpr int K0    = XW0 + DH;     // 224 = 7 k-tiles
constexpr int K1    = DH + DH;      // 256 = 8 k-tiles
constexpr int G4    = 4 * DH;       // 512 gate cols
constexpr int ROWS  = 46;
constexpr int RPAD  = 48;
constexpr int LDX   = XW0 + 8;      // 104 (16B-aligned rows, rotating banks)
constexpr int LDH   = DH + 8;       // 136

__device__ __forceinline__ u16 f2bf(float f) {
    unsigned x = __float_as_uint(f);
    return (u16)((x + 0x7fffu + ((x >> 16) & 1u)) >> 16);   // RNE
}
__device__ __forceinline__ float bf2f(u16 u) { return __uint_as_float(((unsigned)u) << 16); }
__device__ __forceinline__ float sigm(float x)  { return __fdividef(1.f, 1.f + __expf(-x)); }
__device__ __forceinline__ float tanh_f(float x){ return __fdividef(2.f, 1.f + __expf(-2.f * x)) - 1.f; }

// ---------------------------------------------------------------------------
// prep: Wt0[512][224] bf16 = [Wih0 | pad | Whh0], Wt1[512][256] bf16,
// b0,b1 f32 = bih+bhh, Wgt[64][128] bf16 = Wg^T (MFMA-B layout for GCN feat).
// ---------------------------------------------------------------------------
__global__ void k_prep(const float* __restrict__ Wih0, const float* __restrict__ Whh0,
                       const float* __restrict__ bih0, const float* __restrict__ bhh0,
                       const float* __restrict__ Wih1, const float* __restrict__ Whh1,
                       const float* __restrict__ bih1, const float* __restrict__ bhh1,
                       const float* __restrict__ Wg,
                       u16* __restrict__ Wt0, u16* __restrict__ Wt1,
                       float* __restrict__ b0, float* __restrict__ b1,
                       u16* __restrict__ Wgt)
{
    int idx = blockIdx.x * blockDim.x + threadIdx.x;
    const int S0 = G4 * K0, S1 = S0 + G4 * K1;
    const int S2 = S1 + 2 * G4;
    if (idx < S0) {
        int c = idx / K0, k = idx - c * K0;
        float val = 0.f;
        if (k < DOUT + 1) val = Wih0[c * (DOUT + 1) + k];
        else if (k >= XW0) val = Whh0[c * DH + (k - XW0)];
        Wt0[idx] = f2bf(val);
    } else if (idx < S1) {
        int i2 = idx - S0;
        int c = i2 / K1, k = i2 - c * K1;
        float val = (k < DH) ? Wih1[c * DH + k] : Whh1[c * DH + (k - DH)];
        Wt1[i2] = f2bf(val);
    } else if (idx < S1 + G4) {
        int j = idx - S1; b0[j] = bih0[j] + bhh0[j];
    } else if (idx < S2) {
        int j = idx - S1 - G4; b1[j] = bih1[j] + bhh1[j];
    } else if (idx < S2 + DOUT * DIN) {
        int i2 = idx - S2;
        int o = i2 / DIN, k = i2 - o * DIN;
        Wgt[i2] = f2bf(Wg[k * DOUT + o]);
    }
}

// infdot[m] = sum_d x_infection[b][d][n] * fc_w[128+d],  m = n*NB + b
__global__ void k_infdot(const float* __restrict__ xinf, const float* __restrict__ fcw,
                         float* __restrict__ idot)
{
    int m = blockIdx.x * blockDim.x + threadIdx.x;
    if (m < MM) {
        int n = m / NB, b = m - n * NB;
        float s = 0.f;
        for (int d = 0; d < NTX; ++d)
            s += xinf[(b * NTX + d) * NNODE + n] * fcw[DH + d];
        idot[m] = s;
    }
}

// ---------------------------------------------------------------------------
// GCN: one block per (b,t), 4 waves. feat = x@Wg via MFMA (bf16 in, f32 acc);
// DAD + relu + scale in f32. seqb rows stride XW0=96, m = n*NB + b.
// ---------------------------------------------------------------------------
__global__ __launch_bounds__(256)
void k_gcn(const float* __restrict__ x, const float* __restrict__ adjs,
           const float* __restrict__ xinf, const float* __restrict__ dayo,
           const float* __restrict__ v, const u16* __restrict__ Wgt,
           u16* __restrict__ seqb)
{
    int bt = blockIdx.x;              // b*NTX + t
    int b = bt / NTX, t = bt - b * NTX;
    __shared__ __align__(16) u16 sXb[32 * LDH];      // x bf16, rows 23..31 zero
    __shared__ float sA[NNODE * NNODE];
    __shared__ float sdinv[NNODE];
    __shared__ float sscale[NNODE];
    __shared__ float sF[NNODE * 68];                 // feat f32, LDF=68
    int tid = threadIdx.x;
    const int w = tid >> 6, lane = tid & 63, lr = lane & 15, kg = lane >> 4;

    // stage x -> bf16 LDS (float4 coalesced)
    const float* x0 = x + (size_t)bt * NNODE * DIN;
    for (int i = tid; i < 32 * 32; i += 256) {
        int r = i >> 5, c4 = i & 31;
        u16x4 pk;
        if (r < NNODE) {
            float4 val = ((const float4*)x0)[r * 32 + c4];
            pk[0] = f2bf(val.x); pk[1] = f2bf(val.y); pk[2] = f2bf(val.z); pk[3] = f2bf(val.w);
        } else { pk[0] = pk[1] = pk[2] = pk[3] = 0; }
        *(u16x4*)(sXb + r * LDH + c4 * 4) = pk;
    }
    const float* adj0 = adjs + (size_t)bt * NNODE * NNODE;
    for (int i = tid; i < NNODE * NNODE; i += 256) {
        int n = i / NNODE, m2 = i - n * NNODE;
        sA[i] = adj0[i] + (n == m2 ? 1.f : 0.f);
    }
    __syncthreads();

    if (tid < NNODE) {
        float s = 0.f;
        for (int m2 = 0; m2 < NNODE; ++m2) s += sA[tid * NNODE + m2];
        sdinv[tid] = rsqrtf(s);
        float vv = v[tid];
        sscale[tid] = __expf(vv * vv * dayo[b]);
    }

    // feat via MFMA: wave w -> cols 16w..16w+15, two 16-row tiles
    {
        const u16* a0 = sXb + lr * LDH + kg * 8;
        const u16* wb = Wgt + (size_t)(16 * w + lr) * DIN + kg * 8;
        f32x4 acc[2];
#pragma unroll
        for (int m = 0; m < 2; ++m)
#pragma unroll
            for (int q = 0; q < 4; ++q) acc[m][q] = 0.f;
#pragma unroll
        for (int kt = 0; kt < 4; ++kt) {
            bf16x8 Bv  = *(const bf16x8*)(wb + kt * 32);
            bf16x8 A0v = *(const bf16x8*)(a0 + kt * 32);
            bf16x8 A1v = *(const bf16x8*)(a0 + 16 * LDH + kt * 32);
            acc[0] = __builtin_amdgcn_mfma_f32_16x16x32_bf16(A0v, Bv, acc[0], 0, 0, 0);
            acc[1] = __builtin_amdgcn_mfma_f32_16x16x32_bf16(A1v, Bv, acc[1], 0, 0, 0);
        }
#pragma unroll
        for (int m = 0; m < 2; ++m)
#pragma unroll
            for (int q = 0; q < 4; ++q) {
                int r = m * 16 + kg * 4 + q;
                if (r < NNODE) sF[r * 68 + 16 * w + lr] = acc[m][q];
            }
    }
    __syncthreads();

    // DAD + relu + scale (f32)
    for (int i = tid; i < NNODE * DOUT; i += 256) {
        int n = i / DOUT, o = i - n * DOUT;
        float acc = 0.f;
        for (int m2 = 0; m2 < NNODE; ++m2)
            acc = fmaf(sA[n * NNODE + m2] * sdinv[m2], sF[m2 * 68 + o], acc);
        acc *= sdinv[n];
        acc = fmaxf(acc, 0.f) * sscale[n];
        seqb[((size_t)t * MM + n * NB + b) * XW0 + o] = f2bf(acc);
    }
    for (int i = tid; i < NNODE * (XW0 - DOUT - 1); i += 256) {
        int n = i / (XW0 - DOUT - 1), o2 = DOUT + 1 + i - n * (XW0 - DOUT - 1);
        seqb[((size_t)t * MM + n * NB + b) * XW0 + o2] = 0;
    }
    if (tid < NNODE)
        seqb[((size_t)t * MM + tid * NB + b) * XW0 + DOUT] = f2bf(xinf[(size_t)bt * NNODE + tid]);
}

// ---------------------------------------------------------------------------
// GEMM helper: 48x512 gate pre-activations, A split across two LDS tiles at
// k-tile SPLIT. Simple form: fully unrolled, no manual double-buffer — with a
// 256-VGPR budget the compiler schedules loads ahead itself.
// ---------------------------------------------------------------------------
template<int KT, int SPLIT, int LD0, int LD1>
__device__ __forceinline__ void gemm_ab(const u16* A0, const u16* A1,
    const u16* g0, const u16* g1, const u16* g2, const u16* g3,
    f32x4 (&acc)[3][4])
{
#pragma unroll
    for (int m = 0; m < 3; ++m)
#pragma unroll
        for (int g = 0; g < 4; ++g)
#pragma unroll
            for (int q = 0; q < 4; ++q) acc[m][g][q] = 0.f;

#pragma unroll
    for (int kt = 0; kt < KT; ++kt) {
        bf16x8 B0 = *(const bf16x8*)(g0 + kt * 32);
        bf16x8 B1 = *(const bf16x8*)(g1 + kt * 32);
        bf16x8 B2 = *(const bf16x8*)(g2 + kt * 32);
        bf16x8 B3 = *(const bf16x8*)(g3 + kt * 32);
#pragma unroll
        for (int m = 0; m < 3; ++m) {
            bf16x8 Av = *(const bf16x8*)((kt < SPLIT)
                        ? (A0 + m * 16 * LD0 + kt * 32)
                        : (A1 + m * 16 * LD1 + (kt - SPLIT) * 32));
            acc[m][0] = __builtin_amdgcn_mfma_f32_16x16x32_bf16(Av, B0, acc[m][0], 0, 0, 0);
            acc[m][1] = __builtin_amdgcn_mfma_f32_16x16x32_bf16(Av, B1, acc[m][1], 0, 0, 0);
            acc[m][2] = __builtin_amdgcn_mfma_f32_16x16x32_bf16(Av, B2, acc[m][2], 0, 0, 0);
            acc[m][3] = __builtin_amdgcn_mfma_f32_16x16x32_bf16(Av, B3, acc[m][3], 0, 0, 0);
        }
    }
}

__device__ __forceinline__ void epi_plain(const f32x4 (&acc)[3][4], float* cr,
    u16* sHd, float bi, float bf_, float bg, float bo, int kg, int jj)
{
#pragma unroll
    for (int m = 0; m < 3; ++m)
#pragma unroll
        for (int q = 0; q < 4; ++q) {
            int r = m * 16 + kg * 4 + q;
            float gi = acc[m][0][q] + bi, gf = acc[m][1][q] + bf_;
            float gg = acc[m][2][q] + bg, go = acc[m][3][q] + bo;
            float cn = sigm(gf) * cr[m * 4 + q] + sigm(gi) * tanh_f(gg);
            float hn = sigm(go) * tanh_f(cn);
            cr[m * 4 + q] = cn;
            if (r < ROWS) sHd[r * LDH + jj] = f2bf(hn);
        }
}

// ---------------------------------------------------------------------------
// Persistent LSTM scan: 256 blocks x 46 rows x 512 threads (8 waves).
// Whole 28-enc + 7-dec scan in one launch; h0/h1 in LDS, c0/c1 in registers;
// decoder mean accumulated in registers during encoder staging.
// launch_bounds(512,1): grid is exactly 1 block/CU (8 waves), and even at
// 256 VGPR/wave 8 waves/CU fit -> raising the cap costs no occupancy but
// eliminates the 128-VGPR spill (r5: 1.5GB scratch fetch, 186MB write).
// ---------------------------------------------------------------------------
__global__ __launch_bounds__(512, 1)
void k_scan(const u16* __restrict__ seqb,
            const u16* __restrict__ Wt0, const u16* __restrict__ Wt1,
            const float* __restrict__ b0, const float* __restrict__ b1,
            const float* __restrict__ fcw, const float* __restrict__ idot,
            const float* __restrict__ fcbp, float* __restrict__ out)
{
    __shared__ __align__(16) u16 sX [RPAD * LDX];
    __shared__ __align__(16) u16 sH0[RPAD * LDH];
    __shared__ __align__(16) u16 sH1[RPAD * LDH];
    __shared__ float fcbuf[RPAD];
    const int tid = threadIdx.x, w = tid >> 6, lane = tid & 63;
    const int lr = lane & 15, kg = lane >> 4;
    const int row0 = blockIdx.x * ROWS;
    const int jj = 16 * w + lr;

    // zero h state (pad rows stay zero forever; epilogues write only r<46)
    {
        u16x8 z;
#pragma unroll
        for (int q = 0; q < 8; ++q) z[q] = 0;
        for (int i = tid; i < RPAD * (LDH / 8); i += 512) {
            *(u16x8*)(sH0 + i * 8) = z;
            *(u16x8*)(sH1 + i * 8) = z;
        }
    }

    const float bi0 = b0[jj], bf0 = b0[DH + jj], bg0 = b0[2 * DH + jj], bo0 = b0[3 * DH + jj];
    const float bi1 = b1[jj], bf1 = b1[DH + jj], bg1 = b1[2 * DH + jj], bo1 = b1[3 * DH + jj];
    const float fw  = fcw[jj];
    const float fcb = fcbp[0];
    const float idv = (tid < ROWS) ? idot[row0 + tid] : 0.f;

    const u16* aX  = sX  + lr * LDX + kg * 8;
    const u16* aH0 = sH0 + lr * LDH + kg * 8;
    const u16* aH1 = sH1 + lr * LDH + kg * 8;
    const u16* w00 = Wt0 + (size_t)(0 * DH + jj) * K0 + kg * 8;
    const u16* w01 = Wt0 + (size_t)(1 * DH + jj) * K0 + kg * 8;
    const u16* w02 = Wt0 + (size_t)(2 * DH + jj) * K0 + kg * 8;
    const u16* w03 = Wt0 + (size_t)(3 * DH + jj) * K0 + kg * 8;
    const u16* w10 = Wt1 + (size_t)(0 * DH + jj) * K1 + kg * 8;
    const u16* w11 = Wt1 + (size_t)(1 * DH + jj) * K1 + kg * 8;
    const u16* w12 = Wt1 + (size_t)(2 * DH + jj) * K1 + kg * 8;
    const u16* w13 = Wt1 + (size_t)(3 * DH + jj) * K1 + kg * 8;

    float c0r[12], c1r[12];
#pragma unroll
    for (int i = 0; i < 12; ++i) { c0r[i] = 0.f; c1r[i] = 0.f; }
    float xs[16];
#pragma unroll
    for (int i = 0; i < 16; ++i) xs[i] = 0.f;

    f32x4 acc[3][4];

    // ---------------- encoder ----------------
    for (int t = 0; t < NTX; ++t) {
        // stage x tile (48 x 96 bf16) + accumulate decoder mean
#pragma unroll
        for (int ii = 0; ii < 2; ++ii) {
            int i = tid + ii * 512;
            if (i < 576) {
                int r = i / 12, ck = i - r * 12;
                u16x8 val;
                if (r < ROWS) val = *(const u16x8*)(seqb + (size_t)t * MM * XW0 +
                                                   (size_t)(row0 + r) * XW0 + ck * 8);
                else {
#pragma unroll
                    for (int q = 0; q < 8; ++q) val[q] = 0;
                }
                *(u16x8*)(sX + r * LDX + ck * 8) = val;
#pragma unroll
                for (int q = 0; q < 8; ++q) xs[ii * 8 + q] += bf2f(val[q]);
            }
        }
        __syncthreads();
        gemm_ab<7, 3, LDX, LDH>(aX, aH0, w00, w01, w02, w03, acc);
        __syncthreads();
        epi_plain(acc, c0r, sH0, bi0, bf0, bg0, bo0, kg, jj);
        __syncthreads();
        gemm_ab<8, 4, LDH, LDH>(aH0, aH1, w10, w11, w12, w13, acc);
        __syncthreads();
        epi_plain(acc, c1r, sH1, bi1, bf1, bg1, bo1, kg, jj);
        __syncthreads();
    }

    // ---------------- decoder: constant input = mean over encoder days ----
#pragma unroll
    for (int ii = 0; ii < 2; ++ii) {
        int i = tid + ii * 512;
        if (i < 576) {
            int r = i / 12, ck = i - r * 12;
            u16x8 mv;
#pragma unroll
            for (int q = 0; q < 8; ++q) mv[q] = f2bf(xs[ii * 8 + q] * (1.f / NTX));
            *(u16x8*)(sX + r * LDX + ck * 8) = mv;
        }
    }
    __syncthreads();

    for (int t = 0; t < NTY; ++t) {
        if (tid < RPAD) fcbuf[tid] = 0.f;
        gemm_ab<7, 3, LDX, LDH>(aX, aH0, w00, w01, w02, w03, acc);
        __syncthreads();   // gemm reads done + fcbuf zero visible
        epi_plain(acc, c0r, sH0, bi0, bf0, bg0, bo0, kg, jj);
        __syncthreads();
        gemm_ab<8, 4, LDH, LDH>(aH0, aH1, w10, w11, w12, w13, acc);
        __syncthreads();   // L1 gemm reads of sH1 done
        // L1 epilogue + fused FC
#pragma unroll
        for (int m = 0; m < 3; ++m)
#pragma unroll
            for (int q = 0; q < 4; ++q) {
                int r = m * 16 + kg * 4 + q;
                float gi = acc[m][0][q] + bi1, gf = acc[m][1][q] + bf1;
                float gg = acc[m][2][q] + bg1, go = acc[m][3][q] + bo1;
                float cn = sigm(gf) * c1r[m * 4 + q] + sigm(gi) * tanh_f(gg);
                float hn = sigm(go) * tanh_f(cn);
                c1r[m * 4 + q] = cn;
                if (r < ROWS) sH1[r * LDH + jj] = f2bf(hn);
                float p = hn * fw;
                p += __shfl_xor(p, 1, 64);
                p += __shfl_xor(p, 2, 64);
                p += __shfl_xor(p, 4, 64);
                p += __shfl_xor(p, 8, 64);
                if (lr == 0 && r < ROWS) atomicAdd(&fcbuf[r], p);
            }
        __syncthreads();   // atomics done
        if (tid < ROWS) {
            int gr = row0 + tid;
            int n = gr >> 9, bb = gr & (NB - 1);
            out[((size_t)bb * NTY + t) * NNODE + n] = fmaxf(fcbuf[tid] + idv + fcb, 0.f);
        }
        __syncthreads();
    }
}

// ---------------------------------------------------------------------------
extern "C" void kernel_launch(void* const* d_in, const int* in_sizes, int n_in,
                              void* d_out, int out_size, void* d_ws, size_t ws_size,
                              hipStream_t stream)
{
    const float* x    = (const float*)d_in[0];
    const float* adjs = (const float*)d_in[1];
    const float* xinf = (const float*)d_in[2];
    const float* dayo = (const float*)d_in[3];
    const float* v    = (const float*)d_in[4];
    const float* Wg   = (const float*)d_in[5];
    const float* Wih0 = (const float*)d_in[6];
    const float* Whh0 = (const float*)d_in[7];
    const float* bih0 = (const float*)d_in[8];
    const float* bhh0 = (const float*)d_in[9];
    const float* Wih1 = (const float*)d_in[10];
    const float* Whh1 = (const float*)d_in[11];
    const float* bih1 = (const float*)d_in[12];
    const float* bhh1 = (const float*)d_in[13];
    const float* fcw  = (const float*)d_in[14];
    const float* fcb  = (const float*)d_in[15];
    float* out = (float*)d_out;

    char* p = (char*)d_ws;
    auto alloc = [&](size_t bytes) { void* r = p; p += (bytes + 255) & ~(size_t)255; return r; };
    u16*   seqb = (u16*)alloc((size_t)NTX * MM * XW0 * 2);
    u16*   Wt0  = (u16*)alloc((size_t)G4 * K0 * 2);
    u16*   Wt1  = (u16*)alloc((size_t)G4 * K1 * 2);
    u16*   Wgt  = (u16*)alloc((size_t)DOUT * DIN * 2);
    float* b0   = (float*)alloc(G4 * 4);
    float* b1   = (float*)alloc(G4 * 4);
    float* idot = (float*)alloc(MM * 4);

    const int PREP_TOT = G4 * K0 + G4 * K1 + 2 * G4 + DOUT * DIN;
    k_prep<<<(PREP_TOT + 255) / 256, 256, 0, stream>>>(Wih0, Whh0, bih0, bhh0,
                                                       Wih1, Whh1, bih1, bhh1, Wg,
                                                       Wt0, Wt1, b0, b1, Wgt);
    k_infdot<<<(MM + 255) / 256, 256, 0, stream>>>(xinf, fcw, idot);
    k_gcn<<<NB * NTX, 256, 0, stream>>>(x, adjs, xinf, dayo, v, Wgt, seqb);
    k_scan<<<MM / ROWS, 512, 0, stream>>>(seqb, Wt0, Wt1, b0, b1, fcw, idot, fcb, out);
}